// Round 1
// baseline (218.359 us; speedup 1.0000x reference)
//
#include <hip/hip_runtime.h>

#define LOSS_EPS 0.001f
#define EPS_PAR 1e-12f
#define EPS_PT 1e-12f

struct V3 { float x, y, z; };

__device__ __forceinline__ V3 operator-(V3 a, V3 b) { return {a.x - b.x, a.y - b.y, a.z - b.z}; }
__device__ __forceinline__ V3 operator+(V3 a, V3 b) { return {a.x + b.x, a.y + b.y, a.z + b.z}; }
__device__ __forceinline__ V3 operator*(float s, V3 a) { return {s * a.x, s * a.y, s * a.z}; }
__device__ __forceinline__ float dot(V3 a, V3 b) { return a.x * b.x + a.y * b.y + a.z * b.z; }
__device__ __forceinline__ float clamp01(float v) { return fminf(fmaxf(v, 0.0f), 1.0f); }

// Squared segment-segment distance, replicating the reference's exact branch logic.
__device__ __forceinline__ float edge_edge_d2(V3 p1, V3 q1, V3 p2, V3 q2) {
    V3 d1 = q1 - p1;
    V3 d2 = q2 - p2;
    V3 r  = p1 - p2;
    float a = dot(d1, d1);
    float e = dot(d2, d2);
    float f = dot(d2, r);
    float b = dot(d1, d2);
    float c = dot(d1, r);
    float denom = a * e - b * b;
    bool parallel = denom < EPS_PAR;
    float denom_adj = parallel ? 1.0f : denom;
    float s = (b * f - c * e) / denom_adj;
    float t = (a * f - b * c) / denom_adj;
    s = parallel ? 0.0f : s;
    float s_cl = clamp01(s);
    float t_cl = clamp01(t);
    bool recompute_t = (s_cl != s) || parallel;
    V3 r_new = r + s_cl * d1;
    float t_new = clamp01(dot(r_new, d2) / e);
    float t_fin = recompute_t ? t_new : t_cl;
    bool recompute_s = (t_cl != t) && (!parallel) && (s_cl == s);
    V3 r_new2 = r - t_fin * d2;
    float s_new = (-dot(r_new2, d1)) / a;
    float s_fin = recompute_s ? clamp01(s_new) : s_cl;
    V3 c1 = p1 + s_fin * d1;
    V3 c2 = p2 + t_fin * d2;
    V3 diff = c1 - c2;
    return dot(diff, diff);
}

// Squared point-triangle distance (triangle given as the reference's COLUMN vertices).
__device__ __forceinline__ float point_tri_d2(V3 p, V3 v0, V3 v1, V3 v2) {
    V3 e0 = v1 - v0;
    V3 e1 = v2 - v0;
    V3 w  = p - v0;
    float a = fmaxf(dot(e0, e0), EPS_PT);
    float b = dot(e0, e1);
    float c = fmaxf(dot(e1, e1), EPS_PT);
    float d = dot(e0, w);
    float e = dot(e1, w);
    float f = dot(w, w);
    float det = fmaxf(a * c - b * b, EPS_PT);
    float s = b * e - c * d;
    float t = b * d - a * e;
    bool in_face = (s >= 0.0f) && (t >= 0.0f) && (s + t <= det);
    float s01 = clamp01(d / a);
    V3 u01 = w - s01 * e0;
    float d2_e01 = dot(u01, u01);
    float t02 = clamp01(e / c);
    V3 u02 = w - t02 * e1;
    float d2_e02 = dot(u02, u02);
    V3 w2 = p - v1;
    V3 e2 = v2 - v1;
    float a2 = fmaxf(dot(e2, e2), EPS_PT);
    float dd2 = dot(e2, w2);
    float u12 = clamp01(dd2 / a2);
    V3 u12v = w2 - u12 * e2;
    float d2_e12 = dot(u12v, u12v);
    float d2_face = fmaxf((f * det - (d * s + e * t)) / det, 0.0f);
    float d2_edge = fminf(fminf(d2_e01, d2_e02), d2_e12);
    return in_face ? d2_face : d2_edge;
}

__global__ void __launch_bounds__(256)
pen_loss_kernel(const float* __restrict__ tris, const int* __restrict__ idx,
                float* __restrict__ ws, int npairs, int F, int P) {
    int i = blockIdx.x * 256 + threadIdx.x;
    float pen = 0.0f, val = 0.0f;
    if (i < npairs) {
        int b = i / P;
        int rf = idx[2 * i];
        int tf = idx[2 * i + 1];
        val = (rf >= 0) ? 1.0f : 0.0f;
        rf = max(rf, 0);
        tf = max(tf, 0);
        const float* T1 = tris + ((size_t)b * (size_t)F + (size_t)rf) * 9;
        const float* T2 = tris + ((size_t)b * (size_t)F + (size_t)tf) * 9;
        float t1[9], t2[9];
#pragma unroll
        for (int k = 0; k < 9; ++k) { t1[k] = T1[k]; t2[k] = T2[k]; }

        // rows (axis-1 vertices) and cols (axis-2 vertices) per the reference indexing
        V3 r1[3] = { {t1[0], t1[1], t1[2]}, {t1[3], t1[4], t1[5]}, {t1[6], t1[7], t1[8]} };
        V3 c1[3] = { {t1[0], t1[3], t1[6]}, {t1[1], t1[4], t1[7]}, {t1[2], t1[5], t1[8]} };
        V3 r2[3] = { {t2[0], t2[1], t2[2]}, {t2[3], t2[4], t2[5]}, {t2[6], t2[7], t2[8]} };
        V3 c2[3] = { {t2[0], t2[3], t2[6]}, {t2[1], t2[4], t2[7]}, {t2[2], t2[5], t2[8]} };

        float mind2 = 1e30f;
#pragma unroll
        for (int k = 0; k < 3; ++k) {
            mind2 = fminf(mind2, point_tri_d2(r1[k], c2[0], c2[1], c2[2]));
            mind2 = fminf(mind2, point_tri_d2(r2[k], c1[0], c1[1], c1[2]));
        }
#pragma unroll
        for (int ii = 0; ii < 3; ++ii) {
#pragma unroll
            for (int jj = 0; jj < 3; ++jj) {
                mind2 = fminf(mind2, edge_edge_d2(r1[ii], r1[(ii + 1) % 3],
                                                 r2[jj], r2[(jj + 1) % 3]));
            }
        }
        float dist = sqrtf(mind2);
        pen = fmaxf(LOSS_EPS - dist, 0.0f) * val;
    }

    // wave (64-lane) reduction
#pragma unroll
    for (int off = 32; off > 0; off >>= 1) {
        pen += __shfl_down(pen, off);
        val += __shfl_down(val, off);
    }
    __shared__ float sp[4], sv[4];
    int wid = threadIdx.x >> 6;
    if ((threadIdx.x & 63) == 0) { sp[wid] = pen; sv[wid] = val; }
    __syncthreads();
    if (threadIdx.x == 0) {
        float bp = sp[0] + sp[1] + sp[2] + sp[3];
        float bv = sv[0] + sv[1] + sv[2] + sv[3];
        atomicAdd(&ws[0], bp);
        atomicAdd(&ws[1], bv);
    }
}

__global__ void finalize_kernel(const float* __restrict__ ws, float* __restrict__ out) {
    out[0] = ws[0] / fmaxf(ws[1], 1.0f);
}

extern "C" void kernel_launch(void* const* d_in, const int* in_sizes, int n_in,
                              void* d_out, int out_size, void* d_ws, size_t ws_size,
                              hipStream_t stream) {
    const float* tris = (const float*)d_in[0];
    const int* idx = (const int*)d_in[1];
    float* out = (float*)d_out;
    float* ws = (float*)d_ws;

    const int B = 4;
    int F = in_sizes[0] / (B * 9);      // 50000
    int npairs = in_sizes[1] / 2;       // 2,000,000
    int P = npairs / B;                 // 500,000

    hipMemsetAsync(d_ws, 0, 2 * sizeof(float), stream);
    int grid = (npairs + 255) / 256;
    pen_loss_kernel<<<grid, 256, 0, stream>>>(tris, idx, ws, npairs, F, P);
    finalize_kernel<<<1, 1, 0, stream>>>(ws, out);
}

// Round 2
// 216.526 us; speedup vs baseline: 1.0085x; 1.0085x over previous
//
#include <hip/hip_runtime.h>

#define LOSS_EPS 0.001f
#define EPS_PAR 1e-12f
#define EPS_PT 1e-12f

struct V3 { float x, y, z; };

__device__ __forceinline__ V3 operator-(V3 a, V3 b) { return {a.x - b.x, a.y - b.y, a.z - b.z}; }
__device__ __forceinline__ V3 operator+(V3 a, V3 b) { return {a.x + b.x, a.y + b.y, a.z + b.z}; }
__device__ __forceinline__ V3 operator*(float s, V3 a) { return {s * a.x, s * a.y, s * a.z}; }
__device__ __forceinline__ float dot(V3 a, V3 b) { return a.x * b.x + a.y * b.y + a.z * b.z; }
__device__ __forceinline__ float clamp01(float v) { return fminf(fmaxf(v, 0.0f), 1.0f); }
__device__ __forceinline__ float frcp(float x) { return __builtin_amdgcn_rcpf(x); }

// Edge-edge squared distance with precomputed edge norms and reciprocals.
// a = |d1|^2, e = |d2|^2, ra = 1/a, re = 1/e.
__device__ __forceinline__ float edge_edge_d2(V3 p1, V3 d1, V3 p2, V3 d2,
                                              float a, float e, float ra, float re) {
    V3 r = p1 - p2;
    float f = dot(d2, r);
    float b = dot(d1, d2);
    float c = dot(d1, r);
    float denom = a * e - b * b;
    bool parallel = denom < EPS_PAR;
    float rd = frcp(parallel ? 1.0f : denom);
    float s = (b * f - c * e) * rd;
    float t = (a * f - b * c) * rd;
    s = parallel ? 0.0f : s;
    float s_cl = clamp01(s);
    float t_cl = clamp01(t);
    bool recompute_t = (s_cl != s) || parallel;
    V3 r_new = r + s_cl * d1;
    float t_new = clamp01(dot(r_new, d2) * re);
    float t_fin = recompute_t ? t_new : t_cl;
    bool recompute_s = (t_cl != t) && (!parallel) && (s_cl == s);
    V3 r_new2 = r - t_fin * d2;
    float s_new = (-dot(r_new2, d1)) * ra;
    float s_fin = recompute_s ? clamp01(s_new) : s_cl;
    V3 c1 = p1 + s_fin * d1;
    V3 c2 = p2 + t_fin * d2;
    V3 diff = c1 - c2;
    return dot(diff, diff);
}

// Min over 3 points of squared point-triangle distance; triangle invariants hoisted.
__device__ __forceinline__ float ptri3_min_d2(V3 p0, V3 p1, V3 p2,
                                              V3 v0, V3 v1, V3 v2) {
    V3 e0 = v1 - v0;
    V3 e1 = v2 - v0;
    V3 e2t = v2 - v1;
    float a  = fmaxf(dot(e0, e0), EPS_PT);
    float b  = dot(e0, e1);
    float c  = fmaxf(dot(e1, e1), EPS_PT);
    float a2 = fmaxf(dot(e2t, e2t), EPS_PT);
    float det = fmaxf(a * c - b * b, EPS_PT);
    float ra = frcp(a), rc = frcp(c), ra2 = frcp(a2), rdet = frcp(det);

    float best = 1e30f;
    V3 pts[3] = {p0, p1, p2};
#pragma unroll
    for (int k = 0; k < 3; ++k) {
        V3 p = pts[k];
        V3 w = p - v0;
        float d = dot(e0, w);
        float e = dot(e1, w);
        float f = dot(w, w);
        float s = b * e - c * d;
        float t = b * d - a * e;
        bool in_face = (s >= 0.0f) && (t >= 0.0f) && (s + t <= det);
        float s01 = clamp01(d * ra);
        V3 u01 = w - s01 * e0;
        float d2_e01 = dot(u01, u01);
        float t02 = clamp01(e * rc);
        V3 u02 = w - t02 * e1;
        float d2_e02 = dot(u02, u02);
        V3 w2 = p - v1;
        float dd2 = dot(e2t, w2);
        float u12 = clamp01(dd2 * ra2);
        V3 u12v = w2 - u12 * e2t;
        float d2_e12 = dot(u12v, u12v);
        float d2_face = fmaxf((f * det - (d * s + e * t)) * rdet, 0.0f);
        float d2_edge = fminf(fminf(d2_e01, d2_e02), d2_e12);
        best = fminf(best, in_face ? d2_face : d2_edge);
    }
    return best;
}

__global__ void __launch_bounds__(256)
pen_loss_kernel(const float* __restrict__ tris, const int* __restrict__ idx,
                float* __restrict__ ws, int npairs, int F, int P) {
    int i = blockIdx.x * 256 + threadIdx.x;
    float pen = 0.0f, val = 0.0f;
    if (i < npairs) {
        int b = i / P;
        int2 ij = ((const int2*)idx)[i];
        val = (ij.x >= 0) ? 1.0f : 0.0f;
        int rf = max(ij.x, 0);
        int tf = max(ij.y, 0);
        const float* T1 = tris + ((size_t)b * (size_t)F + (size_t)rf) * 9;
        const float* T2 = tris + ((size_t)b * (size_t)F + (size_t)tf) * 9;
        float t1[9], t2[9];
#pragma unroll
        for (int k = 0; k < 9; ++k) { t1[k] = T1[k]; }
#pragma unroll
        for (int k = 0; k < 9; ++k) { t2[k] = T2[k]; }

        // rows (axis-1 vertices) and columns (axis-2 vertices), per reference indexing
        V3 A[3]  = { {t1[0], t1[1], t1[2]}, {t1[3], t1[4], t1[5]}, {t1[6], t1[7], t1[8]} };
        V3 Ac[3] = { {t1[0], t1[3], t1[6]}, {t1[1], t1[4], t1[7]}, {t1[2], t1[5], t1[8]} };
        V3 B[3]  = { {t2[0], t2[1], t2[2]}, {t2[3], t2[4], t2[5]}, {t2[6], t2[7], t2[8]} };
        V3 Bc[3] = { {t2[0], t2[3], t2[6]}, {t2[1], t2[4], t2[7]}, {t2[2], t2[5], t2[8]} };

        float mind2 = 1e30f;
        // point-triangle both directions (triangle passed as COLUMN vertices)
        mind2 = fminf(mind2, ptri3_min_d2(A[0], A[1], A[2], Bc[0], Bc[1], Bc[2]));
        mind2 = fminf(mind2, ptri3_min_d2(B[0], B[1], B[2], Ac[0], Ac[1], Ac[2]));

        // edge vectors + squared norms + reciprocals, hoisted
        V3 dA[3] = { A[1] - A[0], A[2] - A[1], A[0] - A[2] };
        V3 dB[3] = { B[1] - B[0], B[2] - B[1], B[0] - B[2] };
        float la[3], lb[3], rla[3], rlb[3];
#pragma unroll
        for (int k = 0; k < 3; ++k) {
            la[k] = dot(dA[k], dA[k]); rla[k] = frcp(la[k]);
            lb[k] = dot(dB[k], dB[k]); rlb[k] = frcp(lb[k]);
        }
#pragma unroll
        for (int ii = 0; ii < 3; ++ii) {
#pragma unroll
            for (int jj = 0; jj < 3; ++jj) {
                mind2 = fminf(mind2, edge_edge_d2(A[ii], dA[ii], B[jj], dB[jj],
                                                  la[ii], lb[jj], rla[ii], rlb[jj]));
            }
        }
        float dist = sqrtf(mind2);
        pen = fmaxf(LOSS_EPS - dist, 0.0f) * val;
    }

    // wave (64-lane) reduction
#pragma unroll
    for (int off = 32; off > 0; off >>= 1) {
        pen += __shfl_down(pen, off);
        val += __shfl_down(val, off);
    }
    __shared__ float sp[4], sv[4];
    int wid = threadIdx.x >> 6;
    if ((threadIdx.x & 63) == 0) { sp[wid] = pen; sv[wid] = val; }
    __syncthreads();
    if (threadIdx.x == 0) {
        float bp = sp[0] + sp[1] + sp[2] + sp[3];
        float bv = sv[0] + sv[1] + sv[2] + sv[3];
        atomicAdd(&ws[0], bp);
        atomicAdd(&ws[1], bv);
    }
}

__global__ void finalize_kernel(const float* __restrict__ ws, float* __restrict__ out) {
    out[0] = ws[0] / fmaxf(ws[1], 1.0f);
}

extern "C" void kernel_launch(void* const* d_in, const int* in_sizes, int n_in,
                              void* d_out, int out_size, void* d_ws, size_t ws_size,
                              hipStream_t stream) {
    const float* tris = (const float*)d_in[0];
    const int* idx = (const int*)d_in[1];
    float* out = (float*)d_out;
    float* ws = (float*)d_ws;

    const int B = 4;
    int F = in_sizes[0] / (B * 9);      // 50000
    int npairs = in_sizes[1] / 2;       // 2,000,000
    int P = npairs / B;                 // 500,000

    hipMemsetAsync(d_ws, 0, 2 * sizeof(float), stream);
    int grid = (npairs + 255) / 256;
    pen_loss_kernel<<<grid, 256, 0, stream>>>(tris, idx, ws, npairs, F, P);
    finalize_kernel<<<1, 1, 0, stream>>>(ws, out);
}